// Round 6
// baseline (306.512 us; speedup 1.0000x reference)
//
#include <hip/hip_runtime.h>
#include <hip/hip_bf16.h>
#include <cstdint>

#define B_   8
#define S_   2048
#define DIN  512
#define DH   512

typedef __attribute__((ext_vector_type(8))) short  short8;
typedef __attribute__((ext_vector_type(4))) short  short4_;
typedef __attribute__((ext_vector_type(4))) float  float4_;

__device__ inline unsigned short f2bf(float f) {
    union { float f; unsigned u; } v; v.f = f;
    unsigned u = v.u;
    u += 0x7fffu + ((u >> 16) & 1u);   // RNE
    return (unsigned short)(u >> 16);
}

// async global->LDS: per-lane global addr, wave-uniform LDS base (+lane*16 by HW)
__device__ inline void gload_lds16(const void* g, void* l) {
    __builtin_amdgcn_global_load_lds(
        (const __attribute__((address_space(1))) void*)g,
        (__attribute__((address_space(3))) void*)l, 16, 0, 0);
}

// DPP lane-permute within 16-lane rows (VALU, no LDS) — epilogue l-reduce only
template <int C>
__device__ inline float fdpp(float x) {
    return __int_as_float(__builtin_amdgcn_update_dpp(0, __float_as_int(x), C, 0xF, 0xF, true));
}
__device__ inline float rsum16(float v) {
    v += fdpp<0x140>(v);   // row_mirror      (^15)
    v += fdpp<0x141>(v);   // row_half_mirror (^7)
    v += fdpp<27>(v);      // quad_perm [3,2,1,0] (^3)
    v += fdpp<177>(v);     // quad_perm [1,0,3,2] (^1)
    return v;
}

// ---------------------------------------------------------------------------
// Kernel 0: fp32 -> bf16 conversion of x and Wq/Wk/Wv (scratch in d_out).
// ---------------------------------------------------------------------------
__global__ __launch_bounds__(256) void conv_bf16(
    const float* __restrict__ x,
    const float* __restrict__ Wq, const float* __restrict__ Wk, const float* __restrict__ Wv,
    unsigned short* __restrict__ xb, unsigned short* __restrict__ wb)
{
    const int NX4 = (B_ * S_ * DIN) / 4;
    const int NW4 = (DH * DIN) / 4;
    const int total = NX4 + 3 * NW4;
    for (int i = blockIdx.x * blockDim.x + threadIdx.x; i < total;
         i += gridDim.x * blockDim.x) {
        const float4_* src; unsigned short* dst; int j;
        if (i < NX4)             { src = (const float4_*)x;  dst = xb;            j = i; }
        else if (i < NX4 + NW4)  { src = (const float4_*)Wq; dst = wb;            j = i - NX4; }
        else if (i < NX4 + 2*NW4){ src = (const float4_*)Wk; dst = wb + DH*DIN;   j = i - NX4 - NW4; }
        else                     { src = (const float4_*)Wv; dst = wb + 2*DH*DIN; j = i - NX4 - 2*NW4; }
        float4_ v = src[j];
        short4_ o;
        o[0] = (short)f2bf(v[0]); o[1] = (short)f2bf(v[1]);
        o[2] = (short)f2bf(v[2]); o[3] = (short)f2bf(v[3]);
        ((short4_*)dst)[j] = o;
    }
}

// ---------------------------------------------------------------------------
// Kernel 1: QKV projection GEMM with XCD-CHUNKED block swizzle (T1):
// orig dispatch id F -> swz = (F&7)*192 + (F>>3); tm = swz/12, tc = swz%12.
// Each XCD's 192 blocks cover a contiguous 16-panel tm range for ALL 12 tc,
// so the A-panels (2 MB) and B matrices (1.5 MB) are L2-resident per XCD.
// V epilogue writes the TILE-PACKED image vt2[b][tile of 16 keys][dh][32B].
// Q is pre-scaled by log2(e)/sqrt(512) so attn's softmax uses exp2 directly.
// ---------------------------------------------------------------------------
__global__ __launch_bounds__(256) void qkv_gemm(
    const unsigned short* __restrict__ xb,
    const unsigned short* __restrict__ wb,
    const float* __restrict__ bq, const float* __restrict__ bk, const float* __restrict__ bv,
    unsigned short* __restrict__ qws, unsigned short* __restrict__ kws,
    unsigned short* __restrict__ vt2)
{
    __shared__ __align__(16) unsigned short smem[17408];  // 34.8 KB

    const int flat = blockIdx.y * 128 + blockIdx.x;   // HW dispatch order (x fastest)
    const int swz  = (flat & 7) * 192 + (flat >> 3);  // XCD-chunked remap
    const int tm   = swz / 12;
    const int tc   = swz % 12;
    const int mat  = tc >> 2;
    const int nb   = (tc & 3) * 128;
    const int tid  = threadIdx.x;
    const int w    = tid >> 6;
    const int lane = tid & 63;
    const int l15  = lane & 15;
    const int quad = lane >> 4;
    const int wm   = (w & 1) * 64;
    const int wn   = (w >> 1) * 64;
    const int m0   = tm * 128;

    const unsigned short* wmat = wb + (size_t)mat * DH * DIN;

    float4_ zero = {0.f, 0.f, 0.f, 0.f};
    float4_ acc[4][4];
    #pragma unroll
    for (int i = 0; i < 4; i++)
        #pragma unroll
        for (int j = 0; j < 4; j++) acc[i][j] = zero;

    const int lr = lane >> 2;
    const int lb = (lane & 3) * 16;

    auto stage = [&](int kk, int bufi) {
        unsigned short* Ab = smem + bufi * 8192;
        unsigned short* Bb = smem + 4096 + bufi * 8192;
        #pragma unroll
        for (int c = 0; c < 2; c++) {
            int r = w * 32 + c * 16;
            const unsigned char* gA = (const unsigned char*)(xb + (size_t)(m0 + r) * DIN + kk);
            gload_lds16(gA + (size_t)lr * (DIN * 2) + lb, (void*)(Ab + r * 32));
            const unsigned char* gB = (const unsigned char*)(wmat + (size_t)(nb + r) * DIN + kk);
            gload_lds16(gB + (size_t)lr * (DIN * 2) + lb, (void*)(Bb + r * 32));
        }
    };

    stage(0, 0);
    for (int ki = 0; ki < 16; ki++) {
        __syncthreads();
        if (ki < 15) stage((ki + 1) * 32, (ki + 1) & 1);
        const unsigned short* Ab = smem + (ki & 1) * 8192;
        const unsigned short* Bb = smem + 4096 + (ki & 1) * 8192;
        short8 af[4], bf[4];
        #pragma unroll
        for (int mt = 0; mt < 4; mt++)
            af[mt] = *(const short8*)(Ab + (wm + mt * 16 + l15) * 32 + quad * 8);
        #pragma unroll
        for (int nt = 0; nt < 4; nt++)
            bf[nt] = *(const short8*)(Bb + (wn + nt * 16 + l15) * 32 + quad * 8);
        #pragma unroll
        for (int mt = 0; mt < 4; mt++)
            #pragma unroll
            for (int nt = 0; nt < 4; nt++)
                acc[mt][nt] = __builtin_amdgcn_mfma_f32_16x16x32_bf16(af[mt], bf[nt], acc[mt][nt], 0, 0, 0);
    }

    if (mat < 2) {
        const float* bias  = (mat == 0) ? bq : bk;
        // Q scale = log2(e)/sqrt(512): softmax exp(s) == exp2(s*log2e)
        const float  scale = (mat == 0) ? 0.06375870430742225f : 1.0f;
        unsigned short* dst = (mat == 0) ? qws : kws;
        #pragma unroll
        for (int nt = 0; nt < 4; nt++) {
            int n = nb + wn + nt * 16 + l15;
            float bv_ = bias[n];
            #pragma unroll
            for (int mt = 0; mt < 4; mt++) {
                #pragma unroll
                for (int r = 0; r < 4; r++) {
                    int m = m0 + wm + mt * 16 + quad * 4 + r;
                    dst[(size_t)m * DH + n] = f2bf((acc[mt][nt][r] + bv_) * scale);
                }
            }
        }
    } else {
        __syncthreads();
        // build [128 dh_local][128 keys] transpose in LDS (stride 136 shorts)
        unsigned short* trans = smem;
        #pragma unroll
        for (int nt = 0; nt < 4; nt++) {
            int dloc = wn + nt * 16 + l15;
            float bv_ = bv[nb + dloc];
            #pragma unroll
            for (int mt = 0; mt < 4; mt++) {
                short4_ pk;
                #pragma unroll
                for (int r = 0; r < 4; r++) pk[r] = (short)f2bf(acc[mt][nt][r] + bv_);
                *(short4_*)(trans + dloc * 136 + wm + mt * 16 + quad * 4) = pk;
            }
        }
        __syncthreads();
        // store tile-packed image (straight copy, no swizzle)
        int dl   = tid >> 1;           // dh_local 0..127
        int h    = tid & 1;            // key-half
        int dh_g = nb + dl;
        int bi   = m0 >> 11;
        int tile0 = (m0 & 2047) >> 4;  // first tile index within batch
        unsigned char* vt2b = (unsigned char*)vt2;
        #pragma unroll
        for (int t = 0; t < 4; t++) {
            int tl = h * 4 + t;        // tile_local 0..7
            const uint4* c = (const uint4*)(trans + dl * 136 + tl * 16);
            unsigned char* dst = vt2b + ((size_t)(bi * 128 + tile0 + tl) << 14) + dh_g * 32;
            ((uint4*)dst)[0] = c[0];
            ((uint4*)dst)[1] = c[1];
        }
    }
}

// ---------------------------------------------------------------------------
// Kernel 2: flash attention. 256 blocks x 512 threads, 32 iters x 64 keys.
//
// 4 GROUPS x 2 WAVES, 32 q-ROWS PER WAVE: group g owns keys g*512..+512;
// the 2 waves of a group each compute 32q x 16k, so each K-frag (LDS b128)
// feeds TWO MFMAs and each 16-key K-tile is read by 2 waves instead of 4:
// K-LDS-reads drop from 4 KB to 2 KB per key (the round-5 pole).
// V NEVER TOUCHES LDS: per wave 8 coalesced 16B global loads (2x512B
// segments each) issued at the TOP of iter it for PV(it-1) at the END —
// ~2500 cy of slack, zero barrier interaction (V is read-only global).
// PV is cross-4-group K=32: per (qt,dht) two MFMAs, chunk c covering keys
// of groups {2c, 2c+(quad>>1)}; wave w owns dh slice w*64..+64; O spans all
// 2048 keys -> direct store, no O-merge.
// Max-free softmax; P=exp2 (log2e folded into Q); l per-lane VALU + DPP.
// LDS: K 4x2x16KB=128KB + P 4x2x2.5KB=20KB + lbuf 1KB = 149 KB.
// ---------------------------------------------------------------------------
__global__ __launch_bounds__(512, 2) void attn(
    const unsigned short* __restrict__ qws,
    const unsigned short* __restrict__ kws,
    const unsigned short* __restrict__ vt2,
    float* __restrict__ out)
{
    // [0,131072) K: g*32768 + par*16384, 16 rows x 1KB (XOR-swizzled rows)
    // [131072,151552) P: 131072 + g*5120 + par*2560, [64 q][20 shorts]
    // [151552,152576) lbuf [4][64] f32
    __shared__ __align__(16) unsigned char smem[152576];

    const int bid  = blockIdx.x;
    const int b    = bid & 7;              // batch == XCD slot
    const int qt_b = bid >> 3;             // 0..31
    const int tid  = threadIdx.x;
    const int w    = tid >> 6;             // 0..7
    const int g    = w >> 1;               // key-group 0..3 (keys g*512..+512)
    const int h    = w & 1;                // q-half within group (rows h*32..+32)
    const int lane = tid & 63;
    const int l15  = lane & 15;
    const int quad = lane >> 4;

    const int qrow0 = b * S_ + qt_b * 64;

    const unsigned short* kgrp = kws + (size_t)(b * S_ + g * 512) * DH;
    const unsigned char*  vtb  = (const unsigned char*)vt2;

    unsigned char* kb    = smem + g * 32768;            // + par*16384
    unsigned char* pbase = smem + 131072 + g * 5120;    // + par*2560 (write target)
    float*         lbuf  = (float*)(smem + 151552);     // [4][64]

    // Q resident: 32 q-rows (2 q-tiles) = 128 VGPRs
    short8 qf[2][16];
    #pragma unroll
    for (int qi = 0; qi < 2; qi++) {
        const short8* qp = (const short8*)(qws + (size_t)(qrow0 + h * 32 + qi * 16 + l15) * DH);
        #pragma unroll
        for (int ksi = 0; ksi < 16; ksi++) qf[qi][ksi] = qp[ksi * 4 + quad];
    }

    float4_ zero = {0.f, 0.f, 0.f, 0.f};
    float4_ o[16];                 // [qt*4 + dht]: O[64 q][dh slice w*64..+64]
    #pragma unroll
    for (int i = 0; i < 16; i++) o[i] = zero;
    float l_[8];                   // per-lane partial row sums (2 qi x 4 r)
    #pragma unroll
    for (int i = 0; i < 8; i++) l_[i] = 0.f;

    short8 vreg[8];                // V frags [dht*2 + c], direct global loads

    // ---- K staging: tile n of my group; the 2 waves split the 16 rows ----
    auto stageK = [&](int n, int par) {
        #pragma unroll
        for (int i = 0; i < 8; i++) {
            int row = h * 8 + i;
            const unsigned char* gp =
                (const unsigned char*)(kgrp + (size_t)(n * 16 + row) * DH);
            gload_lds16(gp + ((lane ^ (row & 7)) << 4),
                        kb + par * 16384 + row * 1024);
        }
    };

    // ---- V direct global->reg: iter-tile n, my dh slice, both chunks ----
    // chunk c, lane quad: group gc = 2c + (quad>>1), key-half (quad&1).
    auto loadV = [&](int n) {
        #pragma unroll
        for (int dht = 0; dht < 4; dht++)
            #pragma unroll
            for (int c = 0; c < 2; c++) {
                int gc = 2 * c + (quad >> 1);
                const unsigned char* a = vtb
                    + ((size_t)(b * 128 + gc * 32 + n) << 14)
                    + (size_t)(w * 64 + dht * 16 + l15) * 32 + (quad & 1) * 16;
                vreg[dht * 2 + c] = *(const short8*)a;
            }
    };

    // ---- cross-4-group K=32 PV on P parity `par` and vreg ----
    auto doPV = [&](int par) {
        #pragma unroll
        for (int qt = 0; qt < 4; qt++) {
            const int po = (qt * 16 + l15) * 40 + (quad & 1) * 16;
            short8 pa0 = *(const short8*)(smem + 131072 + ( (quad >> 1)     ) * 5120 + par * 2560 + po);
            short8 pa1 = *(const short8*)(smem + 131072 + (2 + (quad >> 1)) * 5120 + par * 2560 + po);
            #pragma unroll
            for (int dht = 0; dht < 4; dht++) {
                o[qt * 4 + dht] = __builtin_amdgcn_mfma_f32_16x16x32_bf16(pa0, vreg[dht * 2 + 0], o[qt * 4 + dht], 0, 0, 0);
                o[qt * 4 + dht] = __builtin_amdgcn_mfma_f32_16x16x32_bf16(pa1, vreg[dht * 2 + 1], o[qt * 4 + dht], 0, 0, 0);
            }
        }
    };

    stageK(0, 0);

    for (int it = 0; it < 32; it++) {
        __syncthreads();   // K(it) staged; P(it-1) visible

        if (it) loadV(it - 1);                       // global->reg, no sync
        if (it < 31) stageK(it + 1, (it + 1) & 1);

        // ---- QK(it): 32 q x 16 keys; each K-frag feeds both q-tiles ----
        const unsigned char* kt_ = kb + (it & 1) * 16384;
        float4_ sA = zero, sB = zero;
        #pragma unroll
        for (int ksi = 0; ksi < 16; ksi++) {
            short8 kf = *(const short8*)(kt_ + l15 * 1024 + (((ksi * 4 + quad) ^ (l15 & 7)) << 4));
            sA = __builtin_amdgcn_mfma_f32_16x16x32_bf16(qf[0][ksi], kf, sA, 0, 0, 0);
            sB = __builtin_amdgcn_mfma_f32_16x16x32_bf16(qf[1][ksi], kf, sB, 0, 0, 0);
        }

        // ---- P(it) = exp2(sc) (max-free; log2e pre-folded into Q) ----
        unsigned short* pp = (unsigned short*)(pbase + (it & 1) * 2560);
        #pragma unroll
        for (int r = 0; r < 4; r++) {
            float p0 = __builtin_exp2f(sA[r]);
            l_[r] += p0;
            pp[(h * 32 + quad * 4 + r) * 20 + l15] = f2bf(p0);
            float p1 = __builtin_exp2f(sB[r]);
            l_[4 + r] += p1;
            pp[(h * 32 + 16 + quad * 4 + r) * 20 + l15] = f2bf(p1);
        }

        // ---- PV(it-1): all 4 groups' keys, my 64-dh slice ----
        if (it) doPV((it - 1) & 1);
    }

    __syncthreads();       // P(31) visible
    loadV(31);
    doPV(1);               // drain tile 31 (parity 1)

    // ---- epilogue: reduce + publish l; direct store ----
    #pragma unroll
    for (int i = 0; i < 8; i++) {
        float s = rsum16(l_[i]);
        if (l15 == 0)
            lbuf[g * 64 + h * 32 + (i >> 2) * 16 + quad * 4 + (i & 3)] = s;
    }
    __syncthreads();

    #pragma unroll
    for (int qt = 0; qt < 4; qt++) {
        float rl[4];
        #pragma unroll
        for (int r = 0; r < 4; r++) {
            int row = qt * 16 + quad * 4 + r;
            rl[r] = 1.f / (lbuf[row] + lbuf[64 + row] + lbuf[128 + row] + lbuf[192 + row]);
        }
        #pragma unroll
        for (int dht = 0; dht < 4; dht++)
            #pragma unroll
            for (int r = 0; r < 4; r++) {
                int row = qt * 16 + quad * 4 + r;
                out[(size_t)(qrow0 + row) * DH + w * 64 + dht * 16 + l15] =
                    o[qt * 4 + dht][r] * rl[r];
            }
    }
}

extern "C" void kernel_launch(void* const* d_in, const int* in_sizes, int n_in,
                              void* d_out, int out_size, void* d_ws, size_t ws_size,
                              hipStream_t stream) {
    const float* x  = (const float*)d_in[0];
    const float* Wq = (const float*)d_in[1];
    const float* bq = (const float*)d_in[2];
    const float* Wk = (const float*)d_in[3];
    const float* bk = (const float*)d_in[4];
    const float* Wv = (const float*)d_in[5];
    const float* bv = (const float*)d_in[6];
    float* out = (float*)d_out;

    unsigned short* qws = (unsigned short*)d_ws;                 // [16384][512] bf16 (pre-scaled)
    unsigned short* kws = qws + (size_t)B_ * S_ * DH;            // [16384][512] bf16
    unsigned short* vt2 = kws + (size_t)B_ * S_ * DH;            // [8][128 tiles][16KB] bf16

    unsigned short* xb = (unsigned short*)d_out;                 // bf16 staging in d_out
    unsigned short* wb = xb + (size_t)B_ * S_ * DIN;

    conv_bf16<<<dim3(2048), dim3(256), 0, stream>>>(x, Wq, Wk, Wv, xb, wb);
    qkv_gemm<<<dim3(128, 12), dim3(256), 0, stream>>>(xb, wb, bq, bk, bv, qws, kws, vt2);
    attn<<<dim3(256), dim3(512), 0, stream>>>(qws, kws, vt2, out);
}

// Round 7
// 271.952 us; speedup vs baseline: 1.1271x; 1.1271x over previous
//
#include <hip/hip_runtime.h>
#include <hip/hip_bf16.h>
#include <cstdint>

#define B_   8
#define S_   2048
#define DIN  512
#define DH   512

typedef __attribute__((ext_vector_type(8))) short  short8;
typedef __attribute__((ext_vector_type(4))) short  short4_;
typedef __attribute__((ext_vector_type(4))) float  float4_;

__device__ inline unsigned short f2bf(float f) {
    union { float f; unsigned u; } v; v.f = f;
    unsigned u = v.u;
    u += 0x7fffu + ((u >> 16) & 1u);   // RNE
    return (unsigned short)(u >> 16);
}

// async global->LDS: per-lane global addr, wave-uniform LDS base (+lane*16 by HW)
__device__ inline void gload_lds16(const void* g, void* l) {
    __builtin_amdgcn_global_load_lds(
        (const __attribute__((address_space(1))) void*)g,
        (__attribute__((address_space(3))) void*)l, 16, 0, 0);
}

// DPP lane-permute within 16-lane rows (VALU, no LDS) — epilogue l-reduce only
template <int C>
__device__ inline float fdpp(float x) {
    return __int_as_float(__builtin_amdgcn_update_dpp(0, __float_as_int(x), C, 0xF, 0xF, true));
}
__device__ inline float rsum16(float v) {
    v += fdpp<0x140>(v);   // row_mirror      (^15)
    v += fdpp<0x141>(v);   // row_half_mirror (^7)
    v += fdpp<27>(v);      // quad_perm [3,2,1,0] (^3)
    v += fdpp<177>(v);     // quad_perm [1,0,3,2] (^1)
    return v;
}

// ---------------------------------------------------------------------------
// Kernel 0: fp32 -> bf16 conversion of x and Wq/Wk/Wv (scratch in d_out).
// ---------------------------------------------------------------------------
__global__ __launch_bounds__(256) void conv_bf16(
    const float* __restrict__ x,
    const float* __restrict__ Wq, const float* __restrict__ Wk, const float* __restrict__ Wv,
    unsigned short* __restrict__ xb, unsigned short* __restrict__ wb)
{
    const int NX4 = (B_ * S_ * DIN) / 4;
    const int NW4 = (DH * DIN) / 4;
    const int total = NX4 + 3 * NW4;
    for (int i = blockIdx.x * blockDim.x + threadIdx.x; i < total;
         i += gridDim.x * blockDim.x) {
        const float4_* src; unsigned short* dst; int j;
        if (i < NX4)             { src = (const float4_*)x;  dst = xb;            j = i; }
        else if (i < NX4 + NW4)  { src = (const float4_*)Wq; dst = wb;            j = i - NX4; }
        else if (i < NX4 + 2*NW4){ src = (const float4_*)Wk; dst = wb + DH*DIN;   j = i - NX4 - NW4; }
        else                     { src = (const float4_*)Wv; dst = wb + 2*DH*DIN; j = i - NX4 - 2*NW4; }
        float4_ v = src[j];
        short4_ o;
        o[0] = (short)f2bf(v[0]); o[1] = (short)f2bf(v[1]);
        o[2] = (short)f2bf(v[2]); o[3] = (short)f2bf(v[3]);
        ((short4_*)dst)[j] = o;
    }
}

// ---------------------------------------------------------------------------
// Kernel 1: QKV projection GEMM, 256(M) x 128(N) tiles, 4 waves (2Mx2N, each
// 128x64). 32 MFMA : 12 ds_read_b128 per k-step (was 16:8); staging bytes
// per output element 16 -> 12; 768 blocks (was 1536) so prologue/epilogue
// amortize better over the short K=512 loop.
// XCD-CHUNKED swizzle (T1): flat -> (flat&7)*96 + (flat>>3); each XCD's 96
// blocks cover a contiguous tm range for all 12 tc (A-panels L2-resident).
// V epilogue writes the TILE-PACKED image vt2[b][tile of 16 keys][dh][32B]
// in TWO key-half passes (trans buffer holds 128 keys at a time).
// Q is pre-scaled by log2(e)/sqrt(512) so attn's softmax uses exp2 directly.
// ---------------------------------------------------------------------------
__global__ __launch_bounds__(256) void qkv_gemm(
    const unsigned short* __restrict__ xb,
    const unsigned short* __restrict__ wb,
    const float* __restrict__ bq, const float* __restrict__ bk, const float* __restrict__ bv,
    unsigned short* __restrict__ qws, unsigned short* __restrict__ kws,
    unsigned short* __restrict__ vt2)
{
    __shared__ __align__(16) unsigned short smem[24576];  // 49.2 KB (A 16K + B 8K, dbuf)

    const int flat = blockIdx.y * 64 + blockIdx.x;    // HW dispatch order (x fastest)
    const int swz  = (flat & 7) * 96 + (flat >> 3);   // XCD-chunked remap (768 = 8*96)
    const int tm   = swz / 12;                        // 0..63
    const int tc   = swz % 12;
    const int mat  = tc >> 2;
    const int nb   = (tc & 3) * 128;
    const int tid  = threadIdx.x;
    const int w    = tid >> 6;
    const int lane = tid & 63;
    const int l15  = lane & 15;
    const int quad = lane >> 4;
    const int wm   = (w & 1) * 128;
    const int wn   = (w >> 1) * 64;
    const int m0   = tm * 256;

    const unsigned short* wmat = wb + (size_t)mat * DH * DIN;

    float4_ zero = {0.f, 0.f, 0.f, 0.f};
    float4_ acc[8][4];
    #pragma unroll
    for (int i = 0; i < 8; i++)
        #pragma unroll
        for (int j = 0; j < 4; j++) acc[i][j] = zero;

    const int lr = lane >> 2;
    const int lb = (lane & 3) * 16;

    auto stage = [&](int kk, int bufi) {
        unsigned short* Ab = smem + bufi * 12288;
        unsigned short* Bb = smem + 8192 + bufi * 12288;
        #pragma unroll
        for (int c = 0; c < 4; c++) {
            int r = w * 64 + c * 16;
            const unsigned char* gA = (const unsigned char*)(xb + (size_t)(m0 + r) * DIN + kk);
            gload_lds16(gA + (size_t)lr * (DIN * 2) + lb, (void*)(Ab + r * 32));
        }
        #pragma unroll
        for (int c = 0; c < 2; c++) {
            int r = w * 32 + c * 16;
            const unsigned char* gB = (const unsigned char*)(wmat + (size_t)(nb + r) * DIN + kk);
            gload_lds16(gB + (size_t)lr * (DIN * 2) + lb, (void*)(Bb + r * 32));
        }
    };

    stage(0, 0);
    for (int ki = 0; ki < 16; ki++) {
        __syncthreads();
        if (ki < 15) stage((ki + 1) * 32, (ki + 1) & 1);
        const unsigned short* Ab = smem + (ki & 1) * 12288;
        const unsigned short* Bb = smem + 8192 + (ki & 1) * 12288;
        short8 af[8], bf[4];
        #pragma unroll
        for (int mt = 0; mt < 8; mt++)
            af[mt] = *(const short8*)(Ab + (wm + mt * 16 + l15) * 32 + quad * 8);
        #pragma unroll
        for (int nt = 0; nt < 4; nt++)
            bf[nt] = *(const short8*)(Bb + (wn + nt * 16 + l15) * 32 + quad * 8);
        #pragma unroll
        for (int mt = 0; mt < 8; mt++)
            #pragma unroll
            for (int nt = 0; nt < 4; nt++)
                acc[mt][nt] = __builtin_amdgcn_mfma_f32_16x16x32_bf16(af[mt], bf[nt], acc[mt][nt], 0, 0, 0);
    }

    if (mat < 2) {
        const float* bias  = (mat == 0) ? bq : bk;
        // Q scale = log2(e)/sqrt(512): softmax exp(s) == exp2(s*log2e)
        const float  scale = (mat == 0) ? 0.06375870430742225f : 1.0f;
        unsigned short* dst = (mat == 0) ? qws : kws;
        #pragma unroll
        for (int nt = 0; nt < 4; nt++) {
            int n = nb + wn + nt * 16 + l15;
            float bv_ = bias[n];
            #pragma unroll
            for (int mt = 0; mt < 8; mt++) {
                #pragma unroll
                for (int r = 0; r < 4; r++) {
                    int m = m0 + wm + mt * 16 + quad * 4 + r;
                    dst[(size_t)m * DH + n] = f2bf((acc[mt][nt][r] + bv_) * scale);
                }
            }
        }
    } else {
        // V: two key-half passes; waves with (w&1)==kh own keys kh*128..+128.
        unsigned short* trans = smem;      // [128 dh][136] shorts
        const int dl   = tid >> 1;         // dh_local 0..127
        const int h2   = tid & 1;          // key-half-of-8-tiles selector
        const int dh_g = nb + dl;
        const int bi   = m0 >> 11;
        unsigned char* vt2b = (unsigned char*)vt2;
        #pragma unroll
        for (int kh = 0; kh < 2; kh++) {
            __syncthreads();
            if ((w & 1) == kh) {
                #pragma unroll
                for (int nt = 0; nt < 4; nt++) {
                    int dloc = wn + nt * 16 + l15;
                    float bv_ = bv[nb + dloc];
                    #pragma unroll
                    for (int mt = 0; mt < 8; mt++) {
                        short4_ pk;
                        #pragma unroll
                        for (int r = 0; r < 4; r++) pk[r] = (short)f2bf(acc[mt][nt][r] + bv_);
                        *(short4_*)(trans + dloc * 136 + mt * 16 + quad * 4) = pk;
                    }
                }
            }
            __syncthreads();
            int tile0 = ((m0 & 2047) >> 4) + kh * 8;
            #pragma unroll
            for (int t = 0; t < 4; t++) {
                int tl = h2 * 4 + t;       // tile_local 0..7
                const uint4* c = (const uint4*)(trans + dl * 136 + tl * 16);
                unsigned char* dst = vt2b + ((size_t)(bi * 128 + tile0 + tl) << 14) + dh_g * 32;
                ((uint4*)dst)[0] = c[0];
                ((uint4*)dst)[1] = c[1];
            }
        }
    }
}

// ---------------------------------------------------------------------------
// Kernel 2: flash attention. 256 blocks x 512 threads, 64 iters.
// Round-5 structure verbatim (142.4 us measured): lag-1 pipelined PV, one
// barrier/iter, stageV(it) with a full iteration of latency slack,
// CROSS-GROUP K=32 PV (quads 0-1 -> g0's 16 keys, 2-3 -> g1's), 8-way dh
// split, O spans all 2048 keys -> direct store, no O-merge.
// Max-free softmax; P = exp2(sc) (log2e pre-folded into Q); l per-lane VALU
// accumulator, DPP-reduced + LDS-merged at the end. No setprio.
// ---------------------------------------------------------------------------
__global__ __launch_bounds__(512, 2) void attn(
    const unsigned short* __restrict__ qws,
    const unsigned short* __restrict__ kws,
    const unsigned short* __restrict__ vt2,
    float* __restrict__ out)
{
    // LDS map: [0,131072) K/V tiles per group: kb = g*65536 (+buf*16384),
    //          vb = g*65536+32768 (+buf*16384);
    // [131072,141312) P dbuf: 131072 + g*5120 + buf*2560, [64][20] bf16;
    // [141312,141824) lbuf [2][64] f32.
    __shared__ __align__(16) unsigned char smem[141824];

    const int bid  = blockIdx.x;
    const int b    = bid & 7;              // batch == XCD slot
    const int qt_b = bid >> 3;             // 0..31
    const int tid  = threadIdx.x;
    const int w    = tid >> 6;             // 0..7
    const int g    = w >> 2;               // key-group (QK role)
    const int wl   = w & 3;                // q-tile within group (QK role)
    const int lane = tid & 63;
    const int l15  = lane & 15;
    const int quad = lane >> 4;

    const int qrow0  = b * S_ + qt_b * 64;
    const int myqrow = qrow0 + wl * 16;

    const unsigned short* kgrp = kws + (size_t)(b * S_ + g * 1024) * DH;
    const unsigned char*  vtb  = (const unsigned char*)vt2;

    unsigned char* kb    = smem + g * 65536;            // + buf*16384
    unsigned char* vb    = smem + g * 65536 + 32768;    // + buf*16384
    unsigned char* pbase = smem + 131072 + g * 5120;    // + buf*2560, [64][20] bf16
    float*         lbuf  = (float*)(smem + 141312);     // [2][64]

    // Q fragments resident (A-operand for QK): 64 VGPRs
    short8 qf[16];
    {
        const short8* qp = (const short8*)(qws + (size_t)(myqrow + l15) * DH);
        #pragma unroll
        for (int ksi = 0; ksi < 16; ksi++) qf[ksi] = qp[ksi * 4 + quad];
    }

    float4_ zero = {0.f, 0.f, 0.f, 0.f};
    float4_ o[16];                 // [qt*4 + dht]: O[64 q][dh slice w*64..+64]
    #pragma unroll
    for (int i = 0; i < 16; i++) o[i] = zero;
    float l_[4] = {0.f, 0.f, 0.f, 0.f};   // per-lane key-partial row sums

    // ---- staging (per group; wave wl does 4 K instrs + 4 V instrs) ----
    auto stageK = [&](int n, int bufi) {
        #pragma unroll
        for (int i = 0; i < 4; i++) {
            int row = wl * 4 + i;
            const unsigned char* gp =
                (const unsigned char*)(kgrp + (size_t)(n * 16 + row) * DH);
            gload_lds16(gp + ((lane ^ (row & 7)) << 4),
                        kb + bufi * 16384 + row * 1024);
        }
    };
    auto stageV = [&](int n, int bufi) {
        const unsigned char* base =
            vtb + ((size_t)(b * 128 + g * 64 + n) << 14) + wl * 4096;
        #pragma unroll
        for (int i = 0; i < 4; i++)
            gload_lds16(base + i * 1024 + lane * 16,
                        vb + bufi * 16384 + wl * 4096 + i * 1024);
    };

    // ---- cross-group K=32 PV on buffer parity `bufi` ----
    auto doPV = [&](int bufi) {
        const unsigned char* pq = smem + 131072 + (quad >> 1) * 5120
                                + bufi * 2560 + (quad & 1) * 16;
        const unsigned char* vq = smem + (quad >> 1) * 65536 + 32768
                                + bufi * 16384 + (quad & 1) * 16;
        short8 pa[4];
        #pragma unroll
        for (int qt = 0; qt < 4; qt++)
            pa[qt] = *(const short8*)(pq + (qt * 16 + l15) * 40);
        #pragma unroll
        for (int dht = 0; dht < 4; dht++) {
            short8 vf = *(const short8*)(vq + (size_t)(w * 64 + dht * 16 + l15) * 32);
            #pragma unroll
            for (int qt = 0; qt < 4; qt++)
                o[qt * 4 + dht] = __builtin_amdgcn_mfma_f32_16x16x32_bf16(pa[qt], vf, o[qt * 4 + dht], 0, 0, 0);
        }
    };

    stageK(0, 0);

    for (int it = 0; it < 64; it++) {
        __syncthreads();   // K(it), V(it-1) staged; P(it-1) visible

        if (it < 63) stageK(it + 1, (it + 1) & 1);
        stageV(it, it & 1);

        // ---- QK(it): 16 q x 16 keys (my group) over d=512 ----
        const unsigned char* kt_ = kb + (it & 1) * 16384;
        float4_ s0 = zero, s1 = zero;
        #pragma unroll
        for (int ksi = 0; ksi < 16; ksi += 2) {
            short8 k0 = *(const short8*)(kt_ + l15 * 1024 + ((( ksi      * 4 + quad) ^ (l15 & 7)) << 4));
            short8 k1 = *(const short8*)(kt_ + l15 * 1024 + ((((ksi + 1) * 4 + quad) ^ (l15 & 7)) << 4));
            s0 = __builtin_amdgcn_mfma_f32_16x16x32_bf16(qf[ksi],     k0, s0, 0, 0, 0);
            s1 = __builtin_amdgcn_mfma_f32_16x16x32_bf16(qf[ksi + 1], k1, s1, 0, 0, 0);
        }
        float4_ sc = s0 + s1;

        // ---- P(it) = exp2(sc) (max-free; log2e pre-folded into Q) ----
        unsigned short* pp = (unsigned short*)(pbase + (it & 1) * 2560);
        #pragma unroll
        for (int r = 0; r < 4; r++) {
            float p = __builtin_exp2f(sc[r]);
            l_[r] += p;
            pp[(wl * 16 + quad * 4 + r) * 20 + l15] = f2bf(p);
        }

        // ---- PV(it-1): both groups' keys, my 64-dh slice ----
        if (it) doPV((it - 1) & 1);
    }

    __syncthreads();       // V(63) staged; P(63) visible
    doPV(1);               // drain tile 63 (buf 1)

    // ---- epilogue: reduce + merge l; direct store (no O-merge) ----
    float lsum[4];
    #pragma unroll
    for (int r = 0; r < 4; r++) lsum[r] = rsum16(l_[r]);
    if (l15 == 0) {
        #pragma unroll
        for (int r = 0; r < 4; r++)
            lbuf[g * 64 + wl * 16 + quad * 4 + r] = lsum[r];
    }
    __syncthreads();

    #pragma unroll
    for (int qt = 0; qt < 4; qt++) {
        float rl[4];
        #pragma unroll
        for (int r = 0; r < 4; r++) {
            int row = qt * 16 + quad * 4 + r;
            rl[r] = 1.f / (lbuf[row] + lbuf[64 + row]);
        }
        #pragma unroll
        for (int dht = 0; dht < 4; dht++)
            #pragma unroll
            for (int r = 0; r < 4; r++) {
                int row = qt * 16 + quad * 4 + r;
                out[(size_t)(qrow0 + row) * DH + w * 64 + dht * 16 + l15] =
                    o[qt * 4 + dht][r] * rl[r];
            }
    }
}

extern "C" void kernel_launch(void* const* d_in, const int* in_sizes, int n_in,
                              void* d_out, int out_size, void* d_ws, size_t ws_size,
                              hipStream_t stream) {
    const float* x  = (const float*)d_in[0];
    const float* Wq = (const float*)d_in[1];
    const float* bq = (const float*)d_in[2];
    const float* Wk = (const float*)d_in[3];
    const float* bk = (const float*)d_in[4];
    const float* Wv = (const float*)d_in[5];
    const float* bv = (const float*)d_in[6];
    float* out = (float*)d_out;

    unsigned short* qws = (unsigned short*)d_ws;                 // [16384][512] bf16 (pre-scaled)
    unsigned short* kws = qws + (size_t)B_ * S_ * DH;            // [16384][512] bf16
    unsigned short* vt2 = kws + (size_t)B_ * S_ * DH;            // [8][128 tiles][16KB] bf16

    unsigned short* xb = (unsigned short*)d_out;                 // bf16 staging in d_out
    unsigned short* wb = xb + (size_t)B_ * S_ * DIN;

    conv_bf16<<<dim3(2048), dim3(256), 0, stream>>>(x, Wq, Wk, Wv, xb, wb);
    qkv_gemm<<<dim3(64, 12), dim3(256), 0, stream>>>(xb, wb, bq, bk, bv, qws, kws, vt2);
    attn<<<dim3(256), dim3(512), 0, stream>>>(qws, kws, vt2, out);
}

// Round 8
// 256.812 us; speedup vs baseline: 1.1935x; 1.0590x over previous
//
#include <hip/hip_runtime.h>
#include <hip/hip_bf16.h>
#include <cstdint>

#define B_   8
#define S_   2048
#define DIN  512
#define DH   512

typedef __attribute__((ext_vector_type(8))) short  short8;
typedef __attribute__((ext_vector_type(4))) short  short4_;
typedef __attribute__((ext_vector_type(4))) float  float4_;

__device__ inline unsigned short f2bf(float f) {
    union { float f; unsigned u; } v; v.f = f;
    unsigned u = v.u;
    u += 0x7fffu + ((u >> 16) & 1u);   // RNE
    return (unsigned short)(u >> 16);
}

// async global->LDS: per-lane global addr, wave-uniform LDS base (+lane*16 by HW)
__device__ inline void gload_lds16(const void* g, void* l) {
    __builtin_amdgcn_global_load_lds(
        (const __attribute__((address_space(1))) void*)g,
        (__attribute__((address_space(3))) void*)l, 16, 0, 0);
}

// DPP lane-permute within 16-lane rows (VALU, no LDS) — epilogue l-reduce only
template <int C>
__device__ inline float fdpp(float x) {
    return __int_as_float(__builtin_amdgcn_update_dpp(0, __float_as_int(x), C, 0xF, 0xF, true));
}
__device__ inline float rsum16(float v) {
    v += fdpp<0x140>(v);   // row_mirror      (^15)
    v += fdpp<0x141>(v);   // row_half_mirror (^7)
    v += fdpp<27>(v);      // quad_perm [3,2,1,0] (^3)
    v += fdpp<177>(v);     // quad_perm [1,0,3,2] (^1)
    return v;
}

// ---------------------------------------------------------------------------
// Kernel 0: fp32 -> bf16 conversion of x and Wq/Wk/Wv (scratch in d_out).
// ---------------------------------------------------------------------------
__global__ __launch_bounds__(256) void conv_bf16(
    const float* __restrict__ x,
    const float* __restrict__ Wq, const float* __restrict__ Wk, const float* __restrict__ Wv,
    unsigned short* __restrict__ xb, unsigned short* __restrict__ wb)
{
    const int NX4 = (B_ * S_ * DIN) / 4;
    const int NW4 = (DH * DIN) / 4;
    const int total = NX4 + 3 * NW4;
    for (int i = blockIdx.x * blockDim.x + threadIdx.x; i < total;
         i += gridDim.x * blockDim.x) {
        const float4_* src; unsigned short* dst; int j;
        if (i < NX4)             { src = (const float4_*)x;  dst = xb;            j = i; }
        else if (i < NX4 + NW4)  { src = (const float4_*)Wq; dst = wb;            j = i - NX4; }
        else if (i < NX4 + 2*NW4){ src = (const float4_*)Wk; dst = wb + DH*DIN;   j = i - NX4 - NW4; }
        else                     { src = (const float4_*)Wv; dst = wb + 2*DH*DIN; j = i - NX4 - 2*NW4; }
        float4_ v = src[j];
        short4_ o;
        o[0] = (short)f2bf(v[0]); o[1] = (short)f2bf(v[1]);
        o[2] = (short)f2bf(v[2]); o[3] = (short)f2bf(v[3]);
        ((short4_*)dst)[j] = o;
    }
}

// ---------------------------------------------------------------------------
// Kernel 1: QKV projection GEMM (round-5 version, 128x128 tiles). V epilogue
// writes the TILE-PACKED image (UNswizzled): vt2[b][tile n of 16 keys][dh][32B].
// Q is pre-scaled by log2(e)/sqrt(512) so attn's softmax uses exp2 directly.
// ---------------------------------------------------------------------------
__global__ __launch_bounds__(256) void qkv_gemm(
    const unsigned short* __restrict__ xb,
    const unsigned short* __restrict__ wb,
    const float* __restrict__ bq, const float* __restrict__ bk, const float* __restrict__ bv,
    unsigned short* __restrict__ qws, unsigned short* __restrict__ kws,
    unsigned short* __restrict__ vt2)
{
    __shared__ __align__(16) unsigned short smem[17408];  // 34.8 KB

    const int tm   = blockIdx.x;
    const int tc   = blockIdx.y;
    const int mat  = tc >> 2;
    const int nb   = (tc & 3) * 128;
    const int tid  = threadIdx.x;
    const int w    = tid >> 6;
    const int lane = tid & 63;
    const int l15  = lane & 15;
    const int quad = lane >> 4;
    const int wm   = (w & 1) * 64;
    const int wn   = (w >> 1) * 64;
    const int m0   = tm * 128;

    const unsigned short* wmat = wb + (size_t)mat * DH * DIN;

    float4_ zero = {0.f, 0.f, 0.f, 0.f};
    float4_ acc[4][4];
    #pragma unroll
    for (int i = 0; i < 4; i++)
        #pragma unroll
        for (int j = 0; j < 4; j++) acc[i][j] = zero;

    const int lr = lane >> 2;
    const int lb = (lane & 3) * 16;

    auto stage = [&](int kk, int bufi) {
        unsigned short* Ab = smem + bufi * 8192;
        unsigned short* Bb = smem + 4096 + bufi * 8192;
        #pragma unroll
        for (int c = 0; c < 2; c++) {
            int r = w * 32 + c * 16;
            const unsigned char* gA = (const unsigned char*)(xb + (size_t)(m0 + r) * DIN + kk);
            gload_lds16(gA + (size_t)lr * (DIN * 2) + lb, (void*)(Ab + r * 32));
            const unsigned char* gB = (const unsigned char*)(wmat + (size_t)(nb + r) * DIN + kk);
            gload_lds16(gB + (size_t)lr * (DIN * 2) + lb, (void*)(Bb + r * 32));
        }
    };

    stage(0, 0);
    for (int ki = 0; ki < 16; ki++) {
        __syncthreads();
        if (ki < 15) stage((ki + 1) * 32, (ki + 1) & 1);
        const unsigned short* Ab = smem + (ki & 1) * 8192;
        const unsigned short* Bb = smem + 4096 + (ki & 1) * 8192;
        short8 af[4], bf[4];
        #pragma unroll
        for (int mt = 0; mt < 4; mt++)
            af[mt] = *(const short8*)(Ab + (wm + mt * 16 + l15) * 32 + quad * 8);
        #pragma unroll
        for (int nt = 0; nt < 4; nt++)
            bf[nt] = *(const short8*)(Bb + (wn + nt * 16 + l15) * 32 + quad * 8);
        #pragma unroll
        for (int mt = 0; mt < 4; mt++)
            #pragma unroll
            for (int nt = 0; nt < 4; nt++)
                acc[mt][nt] = __builtin_amdgcn_mfma_f32_16x16x32_bf16(af[mt], bf[nt], acc[mt][nt], 0, 0, 0);
    }

    if (mat < 2) {
        const float* bias  = (mat == 0) ? bq : bk;
        // Q scale = log2(e)/sqrt(512): softmax exp(s) == exp2(s*log2e)
        const float  scale = (mat == 0) ? 0.06375870430742225f : 1.0f;
        unsigned short* dst = (mat == 0) ? qws : kws;
        #pragma unroll
        for (int nt = 0; nt < 4; nt++) {
            int n = nb + wn + nt * 16 + l15;
            float bv_ = bias[n];
            #pragma unroll
            for (int mt = 0; mt < 4; mt++) {
                #pragma unroll
                for (int r = 0; r < 4; r++) {
                    int m = m0 + wm + mt * 16 + quad * 4 + r;
                    dst[(size_t)m * DH + n] = f2bf((acc[mt][nt][r] + bv_) * scale);
                }
            }
        }
    } else {
        __syncthreads();
        // build [128 dh_local][128 keys] transpose in LDS (stride 136 shorts)
        unsigned short* trans = smem;
        #pragma unroll
        for (int nt = 0; nt < 4; nt++) {
            int dloc = wn + nt * 16 + l15;
            float bv_ = bv[nb + dloc];
            #pragma unroll
            for (int mt = 0; mt < 4; mt++) {
                short4_ pk;
                #pragma unroll
                for (int r = 0; r < 4; r++) pk[r] = (short)f2bf(acc[mt][nt][r] + bv_);
                *(short4_*)(trans + dloc * 136 + wm + mt * 16 + quad * 4) = pk;
            }
        }
        __syncthreads();
        // store tile-packed image (straight copy, no swizzle)
        int dl   = tid >> 1;           // dh_local 0..127
        int h    = tid & 1;            // key-half
        int dh_g = nb + dl;
        int bi   = m0 >> 11;
        int tile0 = (m0 & 2047) >> 4;  // first tile index within batch
        unsigned char* vt2b = (unsigned char*)vt2;
        #pragma unroll
        for (int t = 0; t < 4; t++) {
            int tl = h * 4 + t;        // tile_local 0..7
            const uint4* c = (const uint4*)(trans + dl * 136 + tl * 16);
            unsigned char* dst = vt2b + ((size_t)(bi * 128 + tile0 + tl) << 14) + dh_g * 32;
            ((uint4*)dst)[0] = c[0];
            ((uint4*)dst)[1] = c[1];
        }
    }
}

// ---------------------------------------------------------------------------
// Kernel 2: flash attention. 256 blocks x 512 threads, 64 iters.
// Round-5 skeleton (lag-1 pipelined PV, one barrier/iter, cross-group K=32
// PV, 8-way dh split, direct O store) with ONE change: V NEVER TOUCHES LDS.
// Rationale: each wave reads a disjoint (dh-slice x key) set of V — the
// global->LDS->reg round trip had zero reuse AND its 32B-stride LDS read
// was a 4-way bank conflict (r6 evidence: conflicts 8.39M -> 4.19M when V
// left LDS). V now loads 4 x 16B per wave directly global->reg at the TOP
// of iter it (BEFORE stageK, so the vreg vmcnt-wait leaves K prefetch in
// flight) and is consumed by PV(it-1) at the END — ~4000 cy slack, no
// barrier interaction, byte-identical global traffic (L2-resident: each
// batch's 32 blocks sit on one XCD).
// Max-free softmax; P = exp2(sc) (log2e pre-folded into Q); l per-lane VALU
// accumulator, DPP-reduced + LDS-merged at the end. No setprio.
// ---------------------------------------------------------------------------
__global__ __launch_bounds__(512, 2) void attn(
    const unsigned short* __restrict__ qws,
    const unsigned short* __restrict__ kws,
    const unsigned short* __restrict__ vt2,
    float* __restrict__ out)
{
    // LDS map: [0,65536) K tiles: kb = g*32768 (+buf*16384);
    // [65536,75776) P dbuf: 65536 + g*5120 + buf*2560, [64][20] bf16;
    // [75776,76288) lbuf [2][64] f32.
    __shared__ __align__(16) unsigned char smem[76288];

    const int bid  = blockIdx.x;
    const int b    = bid & 7;              // batch == XCD slot
    const int qt_b = bid >> 3;             // 0..31
    const int tid  = threadIdx.x;
    const int w    = tid >> 6;             // 0..7
    const int g    = w >> 2;               // key-group (QK role)
    const int wl   = w & 3;                // q-tile within group (QK role)
    const int lane = tid & 63;
    const int l15  = lane & 15;
    const int quad = lane >> 4;

    const int qrow0  = b * S_ + qt_b * 64;
    const int myqrow = qrow0 + wl * 16;

    const unsigned short* kgrp = kws + (size_t)(b * S_ + g * 1024) * DH;
    const unsigned char*  vtb  = (const unsigned char*)vt2;

    unsigned char* kb    = smem + g * 32768;            // + buf*16384
    unsigned char* pbase = smem + 65536 + g * 5120;     // + buf*2560, [64][20] bf16
    float*         lbuf  = (float*)(smem + 75776);      // [2][64]

    // Q fragments resident (A-operand for QK): 64 VGPRs
    short8 qf[16];
    {
        const short8* qp = (const short8*)(qws + (size_t)(myqrow + l15) * DH);
        #pragma unroll
        for (int ksi = 0; ksi < 16; ksi++) qf[ksi] = qp[ksi * 4 + quad];
    }

    float4_ zero = {0.f, 0.f, 0.f, 0.f};
    float4_ o[16];                 // [qt*4 + dht]: O[64 q][dh slice w*64..+64]
    #pragma unroll
    for (int i = 0; i < 16; i++) o[i] = zero;
    float l_[4] = {0.f, 0.f, 0.f, 0.f};   // per-lane key-partial row sums

    short8 vreg[4];                // V B-frags [dht], direct global loads (16 VGPR)

    // ---- K staging (per group; wave wl does 4 instrs) ----
    auto stageK = [&](int n, int bufi) {
        #pragma unroll
        for (int i = 0; i < 4; i++) {
            int row = wl * 4 + i;
            const unsigned char* gp =
                (const unsigned char*)(kgrp + (size_t)(n * 16 + row) * DH);
            gload_lds16(gp + ((lane ^ (row & 7)) << 4),
                        kb + bufi * 16384 + row * 1024);
        }
    };

    // ---- V direct global->reg: tile n of group (quad>>1), my dh slice ----
    // Identical bytes the old stageV+LDS-read pair delivered: for lane
    // (l15,quad) the K=32 B-frag k-slot = quad*8+j maps to group quad>>1,
    // key-half quad&1, of the 16-key tile n.
    auto loadV = [&](int n) {
        const unsigned char* base = vtb
            + ((size_t)(b * 128 + (quad >> 1) * 64 + n) << 14) + (quad & 1) * 16;
        #pragma unroll
        for (int dht = 0; dht < 4; dht++)
            vreg[dht] = *(const short8*)(base + (size_t)(w * 64 + dht * 16 + l15) * 32);
    };

    // ---- cross-group K=32 PV: P from LDS parity `bufi`, V from vreg ----
    auto doPV = [&](int bufi) {
        const unsigned char* pq = smem + 65536 + (quad >> 1) * 5120
                                + bufi * 2560 + (quad & 1) * 16;
        short8 pa[4];
        #pragma unroll
        for (int qt = 0; qt < 4; qt++)
            pa[qt] = *(const short8*)(pq + (qt * 16 + l15) * 40);
        #pragma unroll
        for (int dht = 0; dht < 4; dht++) {
            #pragma unroll
            for (int qt = 0; qt < 4; qt++)
                o[qt * 4 + dht] = __builtin_amdgcn_mfma_f32_16x16x32_bf16(pa[qt], vreg[dht], o[qt * 4 + dht], 0, 0, 0);
        }
    };

    stageK(0, 0);

    for (int it = 0; it < 64; it++) {
        __syncthreads();   // K(it) staged; P(it-1) visible

        if (it) loadV(it - 1);                       // V(it-1) global->reg (oldest in queue)
        if (it < 63) stageK(it + 1, (it + 1) & 1);

        // ---- QK(it): 16 q x 16 keys (my group) over d=512 ----
        const unsigned char* kt_ = kb + (it & 1) * 16384;
        float4_ s0 = zero, s1 = zero;
        #pragma unroll
        for (int ksi = 0; ksi < 16; ksi += 2) {
            short8 k0 = *(const short8*)(kt_ + l15 * 1024 + ((( ksi      * 4 + quad) ^ (l15 & 7)) << 4));
            short8 k1 = *(const short8*)(kt_ + l15 * 1024 + ((((ksi + 1) * 4 + quad) ^ (l15 & 7)) << 4));
            s0 = __builtin_amdgcn_mfma_f32_16x16x32_bf16(qf[ksi],     k0, s0, 0, 0, 0);
            s1 = __builtin_amdgcn_mfma_f32_16x16x32_bf16(qf[ksi + 1], k1, s1, 0, 0, 0);
        }
        float4_ sc = s0 + s1;

        // ---- P(it) = exp2(sc) (max-free; log2e pre-folded into Q) ----
        unsigned short* pp = (unsigned short*)(pbase + (it & 1) * 2560);
        #pragma unroll
        for (int r = 0; r < 4; r++) {
            float p = __builtin_exp2f(sc[r]);
            l_[r] += p;
            pp[(wl * 16 + quad * 4 + r) * 20 + l15] = f2bf(p);
        }

        // ---- PV(it-1): both groups' keys, my 64-dh slice ----
        if (it) doPV((it - 1) & 1);
    }

    __syncthreads();       // P(63) visible
    loadV(63);
    doPV(1);               // drain tile 63 (buf 1)

    // ---- epilogue: reduce + merge l; direct store (no O-merge) ----
    float lsum[4];
    #pragma unroll
    for (int r = 0; r < 4; r++) lsum[r] = rsum16(l_[r]);
    if (l15 == 0) {
        #pragma unroll
        for (int r = 0; r < 4; r++)
            lbuf[g * 64 + wl * 16 + quad * 4 + r] = lsum[r];
    }
    __syncthreads();

    #pragma unroll
    for (int qt = 0; qt < 4; qt++) {
        float rl[4];
        #pragma unroll
        for (int r = 0; r < 4; r++) {
            int row = qt * 16 + quad * 4 + r;
            rl[r] = 1.f / (lbuf[row] + lbuf[64 + row]);
        }
        #pragma unroll
        for (int dht = 0; dht < 4; dht++)
            #pragma unroll
            for (int r = 0; r < 4; r++) {
                int row = qt * 16 + quad * 4 + r;
                out[(size_t)(qrow0 + row) * DH + w * 64 + dht * 16 + l15] =
                    o[qt * 4 + dht][r] * rl[r];
            }
    }
}

extern "C" void kernel_launch(void* const* d_in, const int* in_sizes, int n_in,
                              void* d_out, int out_size, void* d_ws, size_t ws_size,
                              hipStream_t stream) {
    const float* x  = (const float*)d_in[0];
    const float* Wq = (const float*)d_in[1];
    const float* bq = (const float*)d_in[2];
    const float* Wk = (const float*)d_in[3];
    const float* bk = (const float*)d_in[4];
    const float* Wv = (const float*)d_in[5];
    const float* bv = (const float*)d_in[6];
    float* out = (float*)d_out;

    unsigned short* qws = (unsigned short*)d_ws;                 // [16384][512] bf16 (pre-scaled)
    unsigned short* kws = qws + (size_t)B_ * S_ * DH;            // [16384][512] bf16
    unsigned short* vt2 = kws + (size_t)B_ * S_ * DH;            // [8][128 tiles][16KB] bf16

    unsigned short* xb = (unsigned short*)d_out;                 // bf16 staging in d_out
    unsigned short* wb = xb + (size_t)B_ * S_ * DIN;

    conv_bf16<<<dim3(2048), dim3(256), 0, stream>>>(x, Wq, Wk, Wv, xb, wb);
    qkv_gemm<<<dim3(128, 12), dim3(256), 0, stream>>>(xb, wb, bq, bk, bv, qws, kws, vt2);
    attn<<<dim3(256), dim3(512), 0, stream>>>(qws, kws, vt2, out);
}